// Round 1
// baseline (384.814 us; speedup 1.0000x reference)
//
#include <hip/hip_runtime.h>

typedef __bf16 bf16x2 __attribute__((ext_vector_type(2)));
typedef __bf16 bf16x8 __attribute__((ext_vector_type(8)));
typedef float f32x4 __attribute__((ext_vector_type(4)));

#define NNODE 8192
#define NHID  256
#define RCAP  128   // raw per-row bucket capacity
#define KCAP  64    // top-k

// ---------------------------------------------------------------- init + dtype probe
__global__ void k_init(int* deg, int* rowcnt, int* flag, const void* edges) {
    int i = blockIdx.x * blockDim.x + threadIdx.x;
    if (i < NNODE) { deg[i] = 0; rowcnt[i] = 0; }
    if (i == 0) {
        // If edge_index is stored as int64, every value read as i64 is in [0, NNODE).
        // If stored as int32, the i64 view mixes two random ints -> huge values.
        const long long* e = (const long long*)edges;
        int ok = 1;
        for (int k = 0; k < 64; ++k) { long long v = e[k]; if (v < 0 || v >= NNODE) ok = 0; }
        *flag = ok;
    }
}

// ---------------------------------------------------------------- scatter edges
__global__ void k_build(const void* edges, const int* flag, int* rowcnt, int* nbr,
                        int* deg, int E) {
    int i = blockIdx.x * blockDim.x + threadIdx.x;
    int total = E + NNODE;
    if (i >= total) return;
    int r, c;
    if (i < E) {
        if (*flag) {
            const long long* e = (const long long*)edges;
            r = (int)e[i]; c = (int)e[E + i];
        } else {
            const int* e = (const int*)edges;
            r = e[i]; c = e[E + i];
        }
    } else {            // self loop
        r = i - E; c = r;
    }
    int pos = atomicAdd(&rowcnt[r], 1);
    if (pos < RCAP) nbr[r * RCAP + pos] = c;
    atomicAdd(&deg[c], 1);
}

// ---------------------------------------------------------------- dedup + weights + top-64
__global__ __launch_bounds__(128) void k_dedup(const int* __restrict__ nbr,
                                               const int* __restrict__ rowcnt,
                                               const int* __restrict__ deg,
                                               int* __restrict__ cols,
                                               float* __restrict__ wout,
                                               float* __restrict__ rsum) {
    __shared__ int lc[RCAP];
    __shared__ float lw[RCAP];
    __shared__ unsigned char kp[RCAP];
    const int r = blockIdx.x, t = threadIdx.x;
    int n = rowcnt[r]; if (n > RCAP) n = RCAP;
    if (t < n) lc[t] = nbr[r * RCAP + t];
    __syncthreads();
    float dr = 1.f / sqrtf((float)deg[r]);
    if (t < n) {
        int c = lc[t];
        int mult = 0; bool first = true;
        for (int i = 0; i < n; ++i) {
            int ci = lc[i];
            if (ci == c) { mult++; if (i < t) first = false; }
        }
        kp[t] = first ? 1 : 0;
        lw[t] = first ? (float)mult * dr * (1.f / sqrtf((float)deg[c])) : 0.f;
    } else if (t < RCAP) { kp[t] = 0; lw[t] = 0.f; }
    __syncthreads();
    if (t == 0) {
        float rs = 0.f; int cnt = 0;
        for (int i = 0; i < n; ++i) { rs += lw[i]; cnt += kp[i]; }
        rsum[r] = rs;                       // full row sum (pre-truncation)
        const int base = r * KCAP;
        if (cnt <= KCAP) {
            int m = 0;
            for (int i = 0; i < n; ++i)
                if (kp[i]) { cols[base + m] = lc[i]; wout[base + m] = lw[i]; m++; }
            for (; m < KCAP; ++m) { cols[base + m] = r; wout[base + m] = 0.f; }
        } else {
            // rare: top-64 by (weight desc, col asc) to match jax top_k tie-break
            for (int s = 0; s < KCAP; ++s) {
                int best = -1;
                for (int i = 0; i < n; ++i) {
                    if (!kp[i]) continue;
                    if (best < 0 || lw[i] > lw[best] ||
                        (lw[i] == lw[best] && lc[i] < lc[best])) best = i;
                }
                cols[base + s] = lc[best]; wout[base + s] = lw[best]; kp[best] = 0;
            }
        }
    }
}

// ---------------------------------------------------------------- fp32 tiled GEMM  C[8192xN256] = A * B
__global__ __launch_bounds__(256) void k_gemm(const float* __restrict__ A,
                                              const float* __restrict__ B,
                                              float* __restrict__ C, int K) {
    __shared__ float As[16][68];
    __shared__ float Bs[16][68];
    const int t = threadIdx.x;
    const int bm = blockIdx.x * 64, bn = blockIdx.y * 64;
    const int ti = t >> 4, tj = t & 15;
    float acc[4][4] = {};
    for (int k0 = 0; k0 < K; k0 += 16) {
#pragma unroll
        for (int rr = 0; rr < 4; ++rr)
            As[t & 15][(t >> 4) + 16 * rr] =
                A[(size_t)(bm + (t >> 4) + 16 * rr) * K + k0 + (t & 15)];
#pragma unroll
        for (int rr = 0; rr < 4; ++rr)
            Bs[(t >> 6) + 4 * rr][t & 63] =
                B[(size_t)(k0 + (t >> 6) + 4 * rr) * NHID + bn + (t & 63)];
        __syncthreads();
#pragma unroll
        for (int kk = 0; kk < 16; ++kk) {
            float4 av = *(const float4*)&As[kk][4 * ti];
            float4 bv = *(const float4*)&Bs[kk][4 * tj];
            const float* ap = (const float*)&av;
            const float* bp = (const float*)&bv;
#pragma unroll
            for (int i = 0; i < 4; ++i)
#pragma unroll
                for (int j = 0; j < 4; ++j)
                    acc[i][j] = fmaf(ap[i], bp[j], acc[i][j]);
        }
        __syncthreads();
    }
#pragma unroll
    for (int i = 0; i < 4; ++i) {
        float4 o = { acc[i][0], acc[i][1], acc[i][2], acc[i][3] };
        *(float4*)&C[(size_t)(bm + 4 * ti + i) * NHID + bn + 4 * tj] = o;
    }
}

// ---------------------------------------------------------------- fused soft-k-medoid + bias + relu
// strides chosen so 16B frag loads spread uniformly over all 8 bank-quads
#define SHI 264   // bf16 row stride for hi (full K=256)
#define SLO 136   // bf16 row stride for lo (half K=128, double-pumped)

__global__ __launch_bounds__(256) void k_medoid(const float* __restrict__ Xin,
                                                const float* __restrict__ bias,
                                                float* __restrict__ Out,
                                                const int* __restrict__ cols,
                                                const float* __restrict__ wts,
                                                const float* __restrict__ rsum) {
    __shared__ __bf16 sh_hi[64][SHI];
    __shared__ __bf16 sh_lo[64][SLO];
    __shared__ float s_a[64];
    __shared__ float s_sq[64];
    __shared__ float s_cpart[4][64];
    __shared__ float s_u[64];
    __shared__ int   s_cols[64];

    const int node = blockIdx.x;
    const int t = threadIdx.x;
    const int w = t >> 6;          // wave id = Gram row-strip
    const int lane = t & 63;
    const int L15 = lane & 15, q = lane >> 4;

    if (t < 64) { s_cols[t] = cols[node * KCAP + t]; s_a[t] = wts[node * KCAP + t]; }
    __syncthreads();

    f32x4 acc[4];
#pragma unroll
    for (int J = 0; J < 4; ++J) acc[J] = (f32x4){0.f, 0.f, 0.f, 0.f};

    const int dI = t & 63;         // float2 index within half-row

    for (int half = 0; half < 2; ++half) {
        // gather 64 rows x 128 dims, split fp32 -> bf16 hi + bf16 lo
        for (int i = 0; i < 16; ++i) {
            int l = i * 4 + w;
            const float2 v = *(const float2*)(Xin + (size_t)s_cols[l] * NHID + half * 128 + 2 * dI);
            __bf16 h0 = (__bf16)v.x, h1 = (__bf16)v.y;
            __bf16 e0 = (__bf16)(v.x - (float)h0), e1 = (__bf16)(v.y - (float)h1);
            bf16x2 hv = {h0, h1}, lv = {e0, e1};
            *(bf16x2*)&sh_hi[l][half * 128 + 2 * dI] = hv;
            *(bf16x2*)&sh_lo[l][2 * dI] = lv;
        }
        __syncthreads();
        // Gram accumulation: G = hi*hi^T + hi*lo^T + lo*hi^T  (A and B^T both row-major)
#pragma unroll
        for (int ks = 0; ks < 4; ++ks) {
            const int koh = half * 128 + ks * 32 + q * 8;
            const int kol = ks * 32 + q * 8;
            bf16x8 ah = *(const bf16x8*)&sh_hi[16 * w + L15][koh];
            bf16x8 al = *(const bf16x8*)&sh_lo[16 * w + L15][kol];
#pragma unroll
            for (int J = 0; J < 4; ++J) {
                bf16x8 bh = *(const bf16x8*)&sh_hi[16 * J + L15][koh];
                bf16x8 bl = *(const bf16x8*)&sh_lo[16 * J + L15][kol];
                acc[J] = __builtin_amdgcn_mfma_f32_16x16x32_bf16(ah, bh, acc[J], 0, 0, 0);
                acc[J] = __builtin_amdgcn_mfma_f32_16x16x32_bf16(ah, bl, acc[J], 0, 0, 0);
                acc[J] = __builtin_amdgcn_mfma_f32_16x16x32_bf16(al, bh, acc[J], 0, 0, 0);
            }
        }
        __syncthreads();
    }

    // sq[l] from Gram diagonal (tile J == w).  C/D layout: col=lane&15, row=q*4+reg
#pragma unroll
    for (int J = 0; J < 4; ++J) {
        if (J == w) {
#pragma unroll
            for (int r = 0; r < 4; ++r)
                if (L15 == q * 4 + r) s_sq[16 * w + L15] = acc[J][r];
        }
    }
    __syncthreads();

    // dist + weighted column sums c[j] = sum_l a[l] * dist(l,j)
#pragma unroll
    for (int J = 0; J < 4; ++J) {
        float pj = 0.f;
#pragma unroll
        for (int r = 0; r < 4; ++r) {
            int row = 16 * w + q * 4 + r;
            int col = 16 * J + L15;
            float d2 = s_sq[row] + s_sq[col] - 2.f * acc[J][r];
            float dist = d2 > 0.f ? sqrtf(d2) : 0.f;
            pj = fmaf(s_a[row], dist, pj);
        }
        pj += __shfl_xor(pj, 16, 64);
        pj += __shfl_xor(pj, 32, 64);
        if (q == 0) s_cpart[w][16 * J + L15] = pj;
    }
    __syncthreads();

    // softmax(-c) * a, renormalized (softmax denominator cancels), * row_sum
    if (w == 0) {
        int j = lane;
        float c = s_cpart[0][j] + s_cpart[1][j] + s_cpart[2][j] + s_cpart[3][j];
        float aj = s_a[j];
        bool valid = aj > 0.f;
        float cv = valid ? c : 3.4e38f;
        float mn = cv;
#pragma unroll
        for (int d = 1; d < 64; d <<= 1) mn = fminf(mn, __shfl_xor(mn, d, 64));
        float e = valid ? expf(mn - c) * aj : 0.f;
        float s = e;
#pragma unroll
        for (int d = 1; d < 64; d <<= 1) s += __shfl_xor(s, d, 64);
        s_u[j] = e * (rsum[node] / s);
    }
    __syncthreads();

    // out[d] = sum_j u[j] * x_j[d]  (hi-only: error averages out in the weighted mean)
    float o = 0.f;
#pragma unroll 16
    for (int j = 0; j < 64; ++j)
        o = fmaf(s_u[j], (float)sh_hi[j][t], o);
    float res = o + bias[t];
    Out[(size_t)node * NHID + t] = fmaxf(res, 0.f);
}

// ---------------------------------------------------------------- launch
extern "C" void kernel_launch(void* const* d_in, const int* in_sizes, int n_in,
                              void* d_out, int out_size, void* d_ws, size_t ws_size,
                              hipStream_t stream) {
    const float* x  = (const float*)d_in[0];
    const void*  ei = d_in[1];
    const float* W1 = (const float*)d_in[2];
    const float* b1 = (const float*)d_in[3];
    const float* W2 = (const float*)d_in[4];
    const float* b2 = (const float*)d_in[5];
    float* out = (float*)d_out;
    const int E = in_sizes[1] / 2;

    char* p = (char*)d_ws;
    auto alloc = [&](size_t bytes) { char* q = p; p += (bytes + 255) & ~(size_t)255; return q; };
    int*   deg    = (int*)alloc((size_t)NNODE * 4);
    int*   rowcnt = (int*)alloc((size_t)NNODE * 4);
    int*   flag   = (int*)alloc(256);
    int*   nbr    = (int*)alloc((size_t)NNODE * RCAP * 4);
    int*   colsA  = (int*)alloc((size_t)NNODE * KCAP * 4);
    float* wA     = (float*)alloc((size_t)NNODE * KCAP * 4);
    float* rsum   = (float*)alloc((size_t)NNODE * 4);
    float* X1     = (float*)alloc((size_t)NNODE * NHID * 4);
    float* H      = (float*)alloc((size_t)NNODE * NHID * 4);
    float* X2     = X1;   // reuse: X1 is dead after first medoid

    k_init<<<(NNODE + 255) / 256, 256, 0, stream>>>(deg, rowcnt, flag, ei);
    k_build<<<(E + NNODE + 255) / 256, 256, 0, stream>>>(ei, flag, rowcnt, nbr, deg, E);
    k_dedup<<<NNODE, 128, 0, stream>>>(nbr, rowcnt, deg, colsA, wA, rsum);

    k_gemm<<<dim3(NNODE / 64, NHID / 64), 256, 0, stream>>>(x, W1, X1, 512);
    k_medoid<<<NNODE, 256, 0, stream>>>(X1, b1, H, colsA, wA, rsum);
    k_gemm<<<dim3(NNODE / 64, NHID / 64), 256, 0, stream>>>(H, W2, X2, 256);
    k_medoid<<<NNODE, 256, 0, stream>>>(X2, b2, out, colsA, wA, rsum);
}

// Round 2
// 325.045 us; speedup vs baseline: 1.1839x; 1.1839x over previous
//
#include <hip/hip_runtime.h>

typedef __bf16 bf16x2 __attribute__((ext_vector_type(2)));
typedef __bf16 bf16x4 __attribute__((ext_vector_type(4)));
typedef __bf16 bf16x8 __attribute__((ext_vector_type(8)));
typedef float f32x4 __attribute__((ext_vector_type(4)));

#define NNODE 8192
#define NHID  256
#define RCAP  128
#define KCAP  64

// ---------------------------------------------------------------- init + dtype probe
__global__ void k_init(int* deg, int* rowcnt, int* flag, const void* edges) {
    int i = blockIdx.x * blockDim.x + threadIdx.x;
    if (i < NNODE) { deg[i] = 0; rowcnt[i] = 0; }
    if (i == 0) {
        const long long* e = (const long long*)edges;
        int ok = 1;
        for (int k = 0; k < 64; ++k) { long long v = e[k]; if (v < 0 || v >= NNODE) ok = 0; }
        *flag = ok;
    }
}

// ---------------------------------------------------------------- scatter edges
__global__ void k_build(const void* edges, const int* flag, int* rowcnt, int* nbr,
                        int* deg, int E) {
    int i = blockIdx.x * blockDim.x + threadIdx.x;
    int total = E + NNODE;
    if (i >= total) return;
    int r, c;
    if (i < E) {
        if (*flag) {
            const long long* e = (const long long*)edges;
            r = (int)e[i]; c = (int)e[E + i];
        } else {
            const int* e = (const int*)edges;
            r = e[i]; c = e[E + i];
        }
    } else { r = i - E; c = r; }
    int pos = atomicAdd(&rowcnt[r], 1);
    if (pos < RCAP) nbr[r * RCAP + pos] = c;
    atomicAdd(&deg[c], 1);
}

// ---------------------------------------------------------------- dedup + weights + top-64
__global__ __launch_bounds__(128) void k_dedup(const int* __restrict__ nbr,
                                               const int* __restrict__ rowcnt,
                                               const int* __restrict__ deg,
                                               int* __restrict__ cols,
                                               float* __restrict__ wout,
                                               float* __restrict__ rsum) {
    __shared__ int lc[RCAP];
    __shared__ float lw[RCAP];
    __shared__ unsigned char kp[RCAP];
    const int r = blockIdx.x, t = threadIdx.x;
    int n = rowcnt[r]; if (n > RCAP) n = RCAP;
    if (t < n) lc[t] = nbr[r * RCAP + t];
    __syncthreads();
    float dr = 1.f / sqrtf((float)deg[r]);
    if (t < n) {
        int c = lc[t];
        int mult = 0; bool first = true;
        for (int i = 0; i < n; ++i) {
            int ci = lc[i];
            if (ci == c) { mult++; if (i < t) first = false; }
        }
        kp[t] = first ? 1 : 0;
        lw[t] = first ? (float)mult * dr * (1.f / sqrtf((float)deg[c])) : 0.f;
    } else if (t < RCAP) { kp[t] = 0; lw[t] = 0.f; }
    __syncthreads();
    if (t == 0) {
        float rs = 0.f; int cnt = 0;
        for (int i = 0; i < n; ++i) { rs += lw[i]; cnt += kp[i]; }
        rsum[r] = rs;
        const int base = r * KCAP;
        if (cnt <= KCAP) {
            int m = 0;
            for (int i = 0; i < n; ++i)
                if (kp[i]) { cols[base + m] = lc[i]; wout[base + m] = lw[i]; m++; }
            for (; m < KCAP; ++m) { cols[base + m] = r; wout[base + m] = 0.f; }
        } else {
            for (int s = 0; s < KCAP; ++s) {
                int best = -1;
                for (int i = 0; i < n; ++i) {
                    if (!kp[i]) continue;
                    if (best < 0 || lw[i] > lw[best] ||
                        (lw[i] == lw[best] && lc[i] < lc[best])) best = i;
                }
                cols[base + s] = lc[best]; wout[base + s] = lw[best]; kp[best] = 0;
            }
        }
    }
}

// ---------------------------------------------------------------- fp32 -> bf16 hi/lo splits
__global__ void k_split4(const float* __restrict__ src, __bf16* __restrict__ hi,
                         __bf16* __restrict__ lo, int n4) {
    int i = blockIdx.x * 256 + threadIdx.x;
    if (i >= n4) return;
    float4 v = ((const float4*)src)[i];
    bf16x4 h, l;
    h[0] = (__bf16)v.x; h[1] = (__bf16)v.y; h[2] = (__bf16)v.z; h[3] = (__bf16)v.w;
    l[0] = (__bf16)(v.x - (float)h[0]); l[1] = (__bf16)(v.y - (float)h[1]);
    l[2] = (__bf16)(v.z - (float)h[2]); l[3] = (__bf16)(v.w - (float)h[3]);
    *(bf16x4*)&hi[4 * (size_t)i] = h;
    *(bf16x4*)&lo[4 * (size_t)i] = l;
}

// split + transpose: out[n][k] = W[k][n]   (N fixed = 256)
__global__ void k_splitT(const float* __restrict__ W, __bf16* __restrict__ hiT,
                         __bf16* __restrict__ loT, int Kdim) {
    int idx = blockIdx.x * 256 + threadIdx.x;
    if (idx >= Kdim * NHID) return;
    int k = idx >> 8, n = idx & 255;
    float v = W[idx];
    __bf16 h = (__bf16)v;
    hiT[(size_t)n * Kdim + k] = h;
    loT[(size_t)n * Kdim + k] = (__bf16)(v - (float)h);
}

// ---------------------------------------------------------------- MFMA GEMM  C[M x 256] = A[M x K] * B[K x 256]
// A given as hi/lo row-major [M][K]; B given as hi/lo TRANSPOSED [256][K].
// 3-product hi/lo: error ~2^-17.  64x64 tile, 4 waves of 32x32.
#define GLS 80   // lds row stride (bf16): 160B = 16B-aligned rows, 40 dw -> conflict-free frags

__global__ __launch_bounds__(256) void k_gemm_mfma(
    const __bf16* __restrict__ Ahi, const __bf16* __restrict__ Alo,
    const __bf16* __restrict__ BThi, const __bf16* __restrict__ BTlo,
    __bf16* __restrict__ Chi, __bf16* __restrict__ Clo, int K) {
    __shared__ __bf16 sA[2][64][GLS];
    __shared__ __bf16 sB[2][64][GLS];
    const int t = threadIdx.x;
    const int bm = blockIdx.x * 64, bn = blockIdx.y * 64;
    const int lane = t & 63, L15 = lane & 15, q = lane >> 4;
    const int w = t >> 6, wr = w >> 1, wc = w & 1;
    f32x4 acc[2][2];
#pragma unroll
    for (int a = 0; a < 2; ++a)
#pragma unroll
        for (int b = 0; b < 2; ++b) acc[a][b] = (f32x4){0.f, 0.f, 0.f, 0.f};

    for (int k0 = 0; k0 < K; k0 += 64) {
#pragma unroll
        for (int i = 0; i < 2; ++i) {
            int idx = t + i * 256;
            int row = idx >> 3, ch = idx & 7;
            size_t ga = (size_t)(bm + row) * K + k0 + ch * 8;
            size_t gb = (size_t)(bn + row) * K + k0 + ch * 8;
            *(bf16x8*)&sA[0][row][ch * 8] = *(const bf16x8*)(Ahi + ga);
            *(bf16x8*)&sA[1][row][ch * 8] = *(const bf16x8*)(Alo + ga);
            *(bf16x8*)&sB[0][row][ch * 8] = *(const bf16x8*)(BThi + gb);
            *(bf16x8*)&sB[1][row][ch * 8] = *(const bf16x8*)(BTlo + gb);
        }
        __syncthreads();
#pragma unroll
        for (int ks = 0; ks < 2; ++ks) {
            const int ko = ks * 32 + q * 8;
            bf16x8 ah[2], al[2], bh[2], bl[2];
#pragma unroll
            for (int tr = 0; tr < 2; ++tr) {
                ah[tr] = *(const bf16x8*)&sA[0][32 * wr + 16 * tr + L15][ko];
                al[tr] = *(const bf16x8*)&sA[1][32 * wr + 16 * tr + L15][ko];
            }
#pragma unroll
            for (int tc = 0; tc < 2; ++tc) {
                bh[tc] = *(const bf16x8*)&sB[0][32 * wc + 16 * tc + L15][ko];
                bl[tc] = *(const bf16x8*)&sB[1][32 * wc + 16 * tc + L15][ko];
            }
#pragma unroll
            for (int tr = 0; tr < 2; ++tr)
#pragma unroll
                for (int tc = 0; tc < 2; ++tc) {
                    acc[tr][tc] = __builtin_amdgcn_mfma_f32_16x16x32_bf16(ah[tr], bh[tc], acc[tr][tc], 0, 0, 0);
                    acc[tr][tc] = __builtin_amdgcn_mfma_f32_16x16x32_bf16(ah[tr], bl[tc], acc[tr][tc], 0, 0, 0);
                    acc[tr][tc] = __builtin_amdgcn_mfma_f32_16x16x32_bf16(al[tr], bh[tc], acc[tr][tc], 0, 0, 0);
                }
        }
        __syncthreads();
    }
    // epilogue: C/D layout col=lane&15, row=q*4+reg; write hi/lo bf16
#pragma unroll
    for (int tr = 0; tr < 2; ++tr)
#pragma unroll
        for (int tc = 0; tc < 2; ++tc)
#pragma unroll
            for (int r = 0; r < 4; ++r) {
                int rowg = bm + 32 * wr + 16 * tr + q * 4 + r;
                int colg = bn + 32 * wc + 16 * tc + L15;
                float v = acc[tr][tc][r];
                __bf16 h = (__bf16)v;
                size_t oi = (size_t)rowg * NHID + colg;
                Chi[oi] = h;
                Clo[oi] = (__bf16)(v - (float)h);
            }
}

// ---------------------------------------------------------------- fused soft-k-medoid + bias + relu
#define SHI 264   // 528B rows: 16B aligned, 132 dw -> conflict-free frags
#define SLO 136   // 272B rows: 16B aligned, 68 dw

__global__ __launch_bounds__(256) void k_medoid(
    const __bf16* __restrict__ Xhi, const __bf16* __restrict__ Xlo,
    const float* __restrict__ bias,
    float* __restrict__ OutF, __bf16* __restrict__ OutHi, __bf16* __restrict__ OutLo,
    const int* __restrict__ cols, const float* __restrict__ wts,
    const float* __restrict__ rsum, int writeBF) {
    __shared__ __bf16 sh_hi[64][SHI];
    __shared__ __bf16 sh_lo[64][SLO];
    __shared__ float s_a[64];
    __shared__ float s_sq[64];
    __shared__ float s_cpart[2][64];
    __shared__ float s_u[64];
    __shared__ int   s_cols[64];

    const int node = blockIdx.x;
    const int t = threadIdx.x;
    const int w = t >> 6, lane = t & 63;
    const int L15 = lane & 15, q = lane >> 4;
    const int wr = w >> 1, wc = w & 1;

    if (t < 64) { s_cols[t] = cols[node * KCAP + t]; s_a[t] = wts[node * KCAP + t]; }
    __syncthreads();

    f32x4 acc[2][2];
#pragma unroll
    for (int a = 0; a < 2; ++a)
#pragma unroll
        for (int b = 0; b < 2; ++b) acc[a][b] = (f32x4){0.f, 0.f, 0.f, 0.f};

    const int ch = lane & 15;         // 16B chunk within half-row
    const int rg = lane >> 4;         // row sub-group

    for (int half = 0; half < 2; ++half) {
        // gather: 16 rows/wave x 128 dims, straight bf16 16B copies (no conversion)
#pragma unroll
        for (int i = 0; i < 4; ++i) {
            int l = (i * 4 + rg) * 4 + w;
            size_t base = ((size_t)s_cols[l] << 8) + half * 128 + ch * 8;
            bf16x8 hv = *(const bf16x8*)(Xhi + base);
            bf16x8 lv = *(const bf16x8*)(Xlo + base);
            *(bf16x8*)&sh_hi[l][half * 128 + ch * 8] = hv;
            *(bf16x8*)&sh_lo[l][ch * 8] = lv;
        }
        __syncthreads();
        // Gram: each wave one 32x32 quadrant (2x2 of 16x16), 3-product hi/lo
#pragma unroll
        for (int ks = 0; ks < 4; ++ks) {
            const int koh = half * 128 + ks * 32 + q * 8;
            const int kol = ks * 32 + q * 8;
            bf16x8 ah[2], al[2], bh[2], bl[2];
#pragma unroll
            for (int tr = 0; tr < 2; ++tr) {
                ah[tr] = *(const bf16x8*)&sh_hi[32 * wr + 16 * tr + L15][koh];
                al[tr] = *(const bf16x8*)&sh_lo[32 * wr + 16 * tr + L15][kol];
            }
#pragma unroll
            for (int tc = 0; tc < 2; ++tc) {
                bh[tc] = *(const bf16x8*)&sh_hi[32 * wc + 16 * tc + L15][koh];
                bl[tc] = *(const bf16x8*)&sh_lo[32 * wc + 16 * tc + L15][kol];
            }
#pragma unroll
            for (int tr = 0; tr < 2; ++tr)
#pragma unroll
                for (int tc = 0; tc < 2; ++tc) {
                    acc[tr][tc] = __builtin_amdgcn_mfma_f32_16x16x32_bf16(ah[tr], bh[tc], acc[tr][tc], 0, 0, 0);
                    acc[tr][tc] = __builtin_amdgcn_mfma_f32_16x16x32_bf16(ah[tr], bl[tc], acc[tr][tc], 0, 0, 0);
                    acc[tr][tc] = __builtin_amdgcn_mfma_f32_16x16x32_bf16(al[tr], bh[tc], acc[tr][tc], 0, 0, 0);
                }
        }
        __syncthreads();
    }

    // diagonal -> s_sq (waves 0 and 3 own the diagonal tiles)
#pragma unroll
    for (int tr = 0; tr < 2; ++tr)
#pragma unroll
        for (int tc = 0; tc < 2; ++tc)
            if (32 * wr + 16 * tr == 32 * wc + 16 * tc) {
#pragma unroll
                for (int r = 0; r < 4; ++r)
                    if (L15 == q * 4 + r) s_sq[32 * wr + 16 * tr + L15] = acc[tr][tc][r];
            }
    __syncthreads();

    // dist + weighted column sums
#pragma unroll
    for (int tc = 0; tc < 2; ++tc) {
        const int colg = 32 * wc + 16 * tc + L15;
        const float sqc = s_sq[colg];
        float pj = 0.f;
#pragma unroll
        for (int tr = 0; tr < 2; ++tr)
#pragma unroll
            for (int r = 0; r < 4; ++r) {
                int rowg = 32 * wr + 16 * tr + q * 4 + r;
                float d2 = s_sq[rowg] + sqc - 2.f * acc[tr][tc][r];
                float dist = d2 > 0.f ? sqrtf(d2) : 0.f;
                pj = fmaf(s_a[rowg], dist, pj);
            }
        pj += __shfl_xor(pj, 16, 64);
        pj += __shfl_xor(pj, 32, 64);
        if (q == 0) s_cpart[wr][colg] = pj;
    }
    __syncthreads();

    // softmax(-c) * a, renormalized, * row_sum
    if (w == 0) {
        int j = lane;
        float c = s_cpart[0][j] + s_cpart[1][j];
        float aj = s_a[j];
        bool valid = aj > 0.f;
        float cv = valid ? c : 3.4e38f;
        float mn = cv;
#pragma unroll
        for (int d = 1; d < 64; d <<= 1) mn = fminf(mn, __shfl_xor(mn, d, 64));
        float e = valid ? expf(mn - c) * aj : 0.f;
        float s = e;
#pragma unroll
        for (int d = 1; d < 64; d <<= 1) s += __shfl_xor(s, d, 64);
        s_u[j] = e * (rsum[node] / s);
    }
    __syncthreads();

    // out[d] = sum_j u[j] * x_j[d]
    float o = 0.f;
#pragma unroll 16
    for (int j = 0; j < 64; ++j)
        o = fmaf(s_u[j], (float)sh_hi[j][t], o);
    float res = fmaxf(o + bias[t], 0.f);
    size_t oi = (size_t)node * NHID + t;
    if (writeBF) {
        __bf16 h = (__bf16)res;
        OutHi[oi] = h;
        OutLo[oi] = (__bf16)(res - (float)h);
    } else {
        OutF[oi] = res;
    }
}

// ---------------------------------------------------------------- launch
extern "C" void kernel_launch(void* const* d_in, const int* in_sizes, int n_in,
                              void* d_out, int out_size, void* d_ws, size_t ws_size,
                              hipStream_t stream) {
    const float* x  = (const float*)d_in[0];
    const void*  ei = d_in[1];
    const float* W1 = (const float*)d_in[2];
    const float* b1 = (const float*)d_in[3];
    const float* W2 = (const float*)d_in[4];
    const float* b2 = (const float*)d_in[5];
    float* out = (float*)d_out;
    const int E = in_sizes[1] / 2;

    char* p = (char*)d_ws;
    auto alloc = [&](size_t bytes) { char* q = p; p += (bytes + 255) & ~(size_t)255; return q; };
    int*    deg    = (int*)alloc((size_t)NNODE * 4);
    int*    rowcnt = (int*)alloc((size_t)NNODE * 4);
    int*    flag   = (int*)alloc(256);
    int*    colsA  = (int*)alloc((size_t)NNODE * KCAP * 4);
    float*  wA     = (float*)alloc((size_t)NNODE * KCAP * 4);
    float*  rsum   = (float*)alloc((size_t)NNODE * 4);
    __bf16* xhi    = (__bf16*)alloc((size_t)NNODE * 512 * 2);
    __bf16* xlo    = (__bf16*)alloc((size_t)NNODE * 512 * 2);
    __bf16* w1Thi  = (__bf16*)alloc((size_t)512 * NHID * 2);
    __bf16* w1Tlo  = (__bf16*)alloc((size_t)512 * NHID * 2);
    __bf16* w2Thi  = (__bf16*)alloc((size_t)NHID * NHID * 2);
    __bf16* w2Tlo  = (__bf16*)alloc((size_t)NHID * NHID * 2);
    __bf16* X1hi   = (__bf16*)alloc((size_t)NNODE * NHID * 2);
    __bf16* X1lo   = (__bf16*)alloc((size_t)NNODE * NHID * 2);
    __bf16* Hhi    = (__bf16*)alloc((size_t)NNODE * NHID * 2);
    __bf16* Hlo    = (__bf16*)alloc((size_t)NNODE * NHID * 2);
    // nbr (4 MB) aliases X1hi/X1lo (8 MB): dead before GEMM1 writes X1
    int* nbr = (int*)X1hi;

    k_init<<<(NNODE + 255) / 256, 256, 0, stream>>>(deg, rowcnt, flag, ei);
    k_build<<<(E + NNODE + 255) / 256, 256, 0, stream>>>(ei, flag, rowcnt, nbr, deg, E);
    k_dedup<<<NNODE, 128, 0, stream>>>(nbr, rowcnt, deg, colsA, wA, rsum);

    k_split4<<<(NNODE * 512 / 4 + 255) / 256, 256, 0, stream>>>(x, xhi, xlo, NNODE * 512 / 4);
    k_splitT<<<(512 * NHID + 255) / 256, 256, 0, stream>>>(W1, w1Thi, w1Tlo, 512);
    k_splitT<<<(NHID * NHID + 255) / 256, 256, 0, stream>>>(W2, w2Thi, w2Tlo, 256);

    k_gemm_mfma<<<dim3(NNODE / 64, NHID / 64), 256, 0, stream>>>(xhi, xlo, w1Thi, w1Tlo, X1hi, X1lo, 512);
    k_medoid<<<NNODE, 256, 0, stream>>>(X1hi, X1lo, b1, nullptr, Hhi, Hlo, colsA, wA, rsum, 1);
    k_gemm_mfma<<<dim3(NNODE / 64, NHID / 64), 256, 0, stream>>>(Hhi, Hlo, w2Thi, w2Tlo, X1hi, X1lo, 256);
    k_medoid<<<NNODE, 256, 0, stream>>>(X1hi, X1lo, b2, out, nullptr, nullptr, colsA, wA, rsum, 0);
}

// Round 3
// 298.147 us; speedup vs baseline: 1.2907x; 1.0902x over previous
//
#include <hip/hip_runtime.h>

typedef __bf16 bf16x2 __attribute__((ext_vector_type(2)));
typedef __bf16 bf16x4 __attribute__((ext_vector_type(4)));
typedef __bf16 bf16x8 __attribute__((ext_vector_type(8)));
typedef float f32x4 __attribute__((ext_vector_type(4)));

#define NNODE 8192
#define NHID  256
#define RCAP  128
#define KCAP  64

// ---------------------------------------------------------------- init + dtype probe
__global__ void k_init(int* deg, int* rowcnt, int* flag, const void* edges) {
    int i = blockIdx.x * blockDim.x + threadIdx.x;
    if (i < NNODE) { deg[i] = 0; rowcnt[i] = 0; }
    if (i == 0) {
        const long long* e = (const long long*)edges;
        int ok = 1;
        for (int k = 0; k < 64; ++k) { long long v = e[k]; if (v < 0 || v >= NNODE) ok = 0; }
        *flag = ok;
    }
}

// ---------------------------------------------------------------- scatter edges
__global__ void k_build(const void* edges, const int* flag, int* rowcnt, int* nbr,
                        int* deg, int E) {
    int i = blockIdx.x * blockDim.x + threadIdx.x;
    int total = E + NNODE;
    if (i >= total) return;
    int r, c;
    if (i < E) {
        if (*flag) {
            const long long* e = (const long long*)edges;
            r = (int)e[i]; c = (int)e[E + i];
        } else {
            const int* e = (const int*)edges;
            r = e[i]; c = e[E + i];
        }
    } else { r = i - E; c = r; }
    int pos = atomicAdd(&rowcnt[r], 1);
    if (pos < RCAP) nbr[r * RCAP + pos] = c;
    atomicAdd(&deg[c], 1);
}

// ---------------------------------------------------------------- dedup + weights + top-64 (wave-parallel)
__global__ __launch_bounds__(128) void k_dedup(const int* __restrict__ nbr,
                                               const int* __restrict__ rowcnt,
                                               const int* __restrict__ deg,
                                               int* __restrict__ cols,
                                               float* __restrict__ wout,
                                               float* __restrict__ rsum) {
    __shared__ int lc[RCAP];
    __shared__ float lw[RCAP];
    __shared__ unsigned char kp[RCAP];
    __shared__ int s_cw[2];
    __shared__ float s_rw[2];
    const int r = blockIdx.x, t = threadIdx.x;
    const int wid = t >> 6, lane = t & 63;
    int n = rowcnt[r]; if (n > RCAP) n = RCAP;
    if (t < n) lc[t] = nbr[r * RCAP + t];
    __syncthreads();
    float dr = 1.f / sqrtf((float)deg[r]);
    bool keep = false; float wv = 0.f;
    if (t < n) {
        int c = lc[t];
        int mult = 0; bool first = true;
        for (int i = 0; i < n; ++i) {
            int ci = lc[i];
            if (ci == c) { mult++; if (i < t) first = false; }
        }
        keep = first;
        if (first) wv = (float)mult * dr * (1.f / sqrtf((float)deg[c]));
    }
    kp[t] = keep ? 1 : 0; lw[t] = wv;
    // wave reduction of row-sum + compaction offsets via ballot
    float rv = wv;
#pragma unroll
    for (int d = 1; d < 64; d <<= 1) rv += __shfl_xor(rv, d, 64);
    unsigned long long b = __ballot(keep);
    int pre = __popcll(b & ((1ull << lane) - 1ull));
    int cw = __popcll(b);
    if (lane == 0) { s_cw[wid] = cw; s_rw[wid] = rv; }
    __syncthreads();
    int total = s_cw[0] + s_cw[1];
    if (t == 0) rsum[r] = s_rw[0] + s_rw[1];
    const int base = r * KCAP;
    if (total <= KCAP) {
        int off = (wid ? s_cw[0] : 0) + pre;
        if (keep) { cols[base + off] = lc[t]; wout[base + off] = wv; }
        for (int m = total + t; m < KCAP; m += 128) { cols[base + m] = r; wout[base + m] = 0.f; }
    } else if (t == 0) {
        // rare fallback: top-64 by (weight desc, col asc)
        for (int s = 0; s < KCAP; ++s) {
            int best = -1;
            for (int i = 0; i < n; ++i) {
                if (!kp[i]) continue;
                if (best < 0 || lw[i] > lw[best] ||
                    (lw[i] == lw[best] && lc[i] < lc[best])) best = i;
            }
            cols[base + s] = lc[best]; wout[base + s] = lw[best]; kp[best] = 0;
        }
    }
}

// ---------------------------------------------------------------- fp32 -> bf16 hi/lo splits
__global__ void k_split4(const float* __restrict__ src, __bf16* __restrict__ hi,
                         __bf16* __restrict__ lo, int n4) {
    int i = blockIdx.x * 256 + threadIdx.x;
    if (i >= n4) return;
    float4 v = ((const float4*)src)[i];
    bf16x4 h, l;
    h[0] = (__bf16)v.x; h[1] = (__bf16)v.y; h[2] = (__bf16)v.z; h[3] = (__bf16)v.w;
    l[0] = (__bf16)(v.x - (float)h[0]); l[1] = (__bf16)(v.y - (float)h[1]);
    l[2] = (__bf16)(v.z - (float)h[2]); l[3] = (__bf16)(v.w - (float)h[3]);
    *(bf16x4*)&hi[4 * (size_t)i] = h;
    *(bf16x4*)&lo[4 * (size_t)i] = l;
}

__global__ void k_splitT(const float* __restrict__ W, __bf16* __restrict__ hiT,
                         __bf16* __restrict__ loT, int Kdim) {
    int idx = blockIdx.x * 256 + threadIdx.x;
    if (idx >= Kdim * NHID) return;
    int k = idx >> 8, n = idx & 255;
    float v = W[idx];
    __bf16 h = (__bf16)v;
    hiT[(size_t)n * Kdim + k] = h;
    loT[(size_t)n * Kdim + k] = (__bf16)(v - (float)h);
}

// ---------------------------------------------------------------- MFMA GEMM  C[M x 256] = A[M x K] * B[K x 256]
#define GLS 72   // 36 dw row stride: 9 quads/row -> consecutive rows hit consecutive bank-quads

__global__ __launch_bounds__(256) void k_gemm_mfma(
    const __bf16* __restrict__ Ahi, const __bf16* __restrict__ Alo,
    const __bf16* __restrict__ BThi, const __bf16* __restrict__ BTlo,
    __bf16* __restrict__ Chi, __bf16* __restrict__ Clo, int K) {
    __shared__ __bf16 sA[2][64][GLS];
    __shared__ __bf16 sB[2][64][GLS];
    const int t = threadIdx.x;
    const int bm = blockIdx.x * 64, bn = blockIdx.y * 64;
    const int lane = t & 63, L15 = lane & 15, q = lane >> 4;
    const int w = t >> 6, wr = w >> 1, wc = w & 1;
    f32x4 acc[2][2];
#pragma unroll
    for (int a = 0; a < 2; ++a)
#pragma unroll
        for (int b = 0; b < 2; ++b) acc[a][b] = (f32x4){0.f, 0.f, 0.f, 0.f};

    for (int k0 = 0; k0 < K; k0 += 64) {
#pragma unroll
        for (int i = 0; i < 2; ++i) {
            int idx = t + i * 256;
            int row = idx >> 3, ch = idx & 7;
            size_t ga = (size_t)(bm + row) * K + k0 + ch * 8;
            size_t gb = (size_t)(bn + row) * K + k0 + ch * 8;
            *(bf16x8*)&sA[0][row][ch * 8] = *(const bf16x8*)(Ahi + ga);
            *(bf16x8*)&sA[1][row][ch * 8] = *(const bf16x8*)(Alo + ga);
            *(bf16x8*)&sB[0][row][ch * 8] = *(const bf16x8*)(BThi + gb);
            *(bf16x8*)&sB[1][row][ch * 8] = *(const bf16x8*)(BTlo + gb);
        }
        __syncthreads();
#pragma unroll
        for (int ks = 0; ks < 2; ++ks) {
            const int ko = ks * 32 + q * 8;
            bf16x8 ah[2], al[2], bh[2], bl[2];
#pragma unroll
            for (int tr = 0; tr < 2; ++tr) {
                ah[tr] = *(const bf16x8*)&sA[0][32 * wr + 16 * tr + L15][ko];
                al[tr] = *(const bf16x8*)&sA[1][32 * wr + 16 * tr + L15][ko];
            }
#pragma unroll
            for (int tc = 0; tc < 2; ++tc) {
                bh[tc] = *(const bf16x8*)&sB[0][32 * wc + 16 * tc + L15][ko];
                bl[tc] = *(const bf16x8*)&sB[1][32 * wc + 16 * tc + L15][ko];
            }
#pragma unroll
            for (int tr = 0; tr < 2; ++tr)
#pragma unroll
                for (int tc = 0; tc < 2; ++tc) {
                    acc[tr][tc] = __builtin_amdgcn_mfma_f32_16x16x32_bf16(ah[tr], bh[tc], acc[tr][tc], 0, 0, 0);
                    acc[tr][tc] = __builtin_amdgcn_mfma_f32_16x16x32_bf16(ah[tr], bl[tc], acc[tr][tc], 0, 0, 0);
                    acc[tr][tc] = __builtin_amdgcn_mfma_f32_16x16x32_bf16(al[tr], bh[tc], acc[tr][tc], 0, 0, 0);
                }
        }
        __syncthreads();
    }
#pragma unroll
    for (int tr = 0; tr < 2; ++tr)
#pragma unroll
        for (int tc = 0; tc < 2; ++tc)
#pragma unroll
            for (int r = 0; r < 4; ++r) {
                int rowg = bm + 32 * wr + 16 * tr + q * 4 + r;
                int colg = bn + 32 * wc + 16 * tc + L15;
                float v = acc[tr][tc][r];
                __bf16 h = (__bf16)v;
                size_t oi = (size_t)rowg * NHID + colg;
                Chi[oi] = h;
                Clo[oi] = (__bf16)(v - (float)h);
            }
}

// ---------------------------------------------------------------- fused soft-k-medoid + bias + relu
// half-K LDS tiles (both halves accumulate into the same AGPRs) -> 36.3 KB -> 4 blocks/CU
#define SK 136   // 68 dw rows = 17 quads: consecutive rows hit consecutive bank-quads

__global__ __launch_bounds__(256, 4) void k_medoid(
    const __bf16* __restrict__ Xhi, const __bf16* __restrict__ Xlo,
    const float* __restrict__ bias,
    float* __restrict__ OutF, __bf16* __restrict__ OutHi, __bf16* __restrict__ OutLo,
    const int* __restrict__ cols, const float* __restrict__ wts,
    const float* __restrict__ rsum, int writeBF) {
    __shared__ __bf16 sh_hi[64][SK];
    __shared__ __bf16 sh_lo[64][SK];
    __shared__ float s_a[64];
    __shared__ float s_sq[64];
    __shared__ float s_cpart[2][64];
    __shared__ float s_u[64];
    __shared__ int   s_cols[64];

    const int node = blockIdx.x;
    const int t = threadIdx.x;
    const int w = t >> 6, lane = t & 63;
    const int L15 = lane & 15, q = lane >> 4;
    const int wr = w >> 1, wc = w & 1;

    if (t < 64) { s_cols[t] = cols[node * KCAP + t]; s_a[t] = wts[node * KCAP + t]; }
    __syncthreads();

    f32x4 acc[2][2];
#pragma unroll
    for (int a = 0; a < 2; ++a)
#pragma unroll
        for (int b = 0; b < 2; ++b) acc[a][b] = (f32x4){0.f, 0.f, 0.f, 0.f};

    const int ch = lane & 15;
    const int rg = lane >> 4;

    for (int half = 0; half < 2; ++half) {
        // gather: 64 rows x 128 dims of hi+lo, 16B copies
#pragma unroll
        for (int i = 0; i < 4; ++i) {
            int l = (i * 4 + rg) * 4 + w;
            size_t base = ((size_t)s_cols[l] << 8) + half * 128 + ch * 8;
            *(bf16x8*)&sh_hi[l][ch * 8] = *(const bf16x8*)(Xhi + base);
            *(bf16x8*)&sh_lo[l][ch * 8] = *(const bf16x8*)(Xlo + base);
        }
        __syncthreads();
        // Gram quadrant per wave, 3-product hi/lo, acc carried across halves
#pragma unroll
        for (int ks = 0; ks < 4; ++ks) {
            const int ko = ks * 32 + q * 8;
            bf16x8 ah[2], al[2], bh[2], bl[2];
#pragma unroll
            for (int tr = 0; tr < 2; ++tr) {
                ah[tr] = *(const bf16x8*)&sh_hi[32 * wr + 16 * tr + L15][ko];
                al[tr] = *(const bf16x8*)&sh_lo[32 * wr + 16 * tr + L15][ko];
            }
#pragma unroll
            for (int tc = 0; tc < 2; ++tc) {
                bh[tc] = *(const bf16x8*)&sh_hi[32 * wc + 16 * tc + L15][ko];
                bl[tc] = *(const bf16x8*)&sh_lo[32 * wc + 16 * tc + L15][ko];
            }
#pragma unroll
            for (int tr = 0; tr < 2; ++tr)
#pragma unroll
                for (int tc = 0; tc < 2; ++tc) {
                    acc[tr][tc] = __builtin_amdgcn_mfma_f32_16x16x32_bf16(ah[tr], bh[tc], acc[tr][tc], 0, 0, 0);
                    acc[tr][tc] = __builtin_amdgcn_mfma_f32_16x16x32_bf16(ah[tr], bl[tc], acc[tr][tc], 0, 0, 0);
                    acc[tr][tc] = __builtin_amdgcn_mfma_f32_16x16x32_bf16(al[tr], bh[tc], acc[tr][tc], 0, 0, 0);
                }
        }
        __syncthreads();
    }
    // NOTE: sh_hi still holds half=1 (dims 128..255) — reused by the epilogue.

    // diagonal -> s_sq
#pragma unroll
    for (int tr = 0; tr < 2; ++tr)
#pragma unroll
        for (int tc = 0; tc < 2; ++tc)
            if (32 * wr + 16 * tr == 32 * wc + 16 * tc) {
#pragma unroll
                for (int r = 0; r < 4; ++r)
                    if (L15 == q * 4 + r) s_sq[32 * wr + 16 * tr + L15] = acc[tr][tc][r];
            }
    __syncthreads();

    // dist + weighted column sums
#pragma unroll
    for (int tc = 0; tc < 2; ++tc) {
        const int colg = 32 * wc + 16 * tc + L15;
        const float sqc = s_sq[colg];
        float pj = 0.f;
#pragma unroll
        for (int tr = 0; tr < 2; ++tr)
#pragma unroll
            for (int r = 0; r < 4; ++r) {
                int rowg = 32 * wr + 16 * tr + q * 4 + r;
                float d2 = s_sq[rowg] + sqc - 2.f * acc[tr][tc][r];
                float dist = d2 > 0.f ? __builtin_amdgcn_sqrtf(d2) : 0.f;
                pj = fmaf(s_a[rowg], dist, pj);
            }
        pj += __shfl_xor(pj, 16, 64);
        pj += __shfl_xor(pj, 32, 64);
        if (q == 0) s_cpart[wr][colg] = pj;
    }
    __syncthreads();

    // softmax(-c) * a, renormalized, * row_sum
    if (w == 0) {
        int j = lane;
        float c = s_cpart[0][j] + s_cpart[1][j];
        float aj = s_a[j];
        bool valid = aj > 0.f;
        float cv = valid ? c : 3.4e38f;
        float mn = cv;
#pragma unroll
        for (int d = 1; d < 64; d <<= 1) mn = fminf(mn, __shfl_xor(mn, d, 64));
        float e = valid ? __expf(mn - c) * aj : 0.f;
        float s = e;
#pragma unroll
        for (int d = 1; d < 64; d <<= 1) s += __shfl_xor(s, d, 64);
        s_u[j] = e * (rsum[node] / s);
    }
    __syncthreads();

    // out[d] = sum_j u[j] * x_j[d]
    // waves 0-1: dims 0..127 from global (coalesced, L2-hot); waves 2-3: dims 128..255 from LDS
    float o = 0.f;
    if (w < 2) {
#pragma unroll 8
        for (int j = 0; j < 64; ++j)
            o = fmaf(s_u[j], (float)Xhi[((size_t)s_cols[j] << 8) + t], o);
    } else {
        const int dl = t - 128;
#pragma unroll 8
        for (int j = 0; j < 64; ++j)
            o = fmaf(s_u[j], (float)sh_hi[j][dl], o);
    }
    float res = fmaxf(o + bias[t], 0.f);
    size_t oi = (size_t)node * NHID + t;
    if (writeBF) {
        __bf16 h = (__bf16)res;
        OutHi[oi] = h;
        OutLo[oi] = (__bf16)(res - (float)h);
    } else {
        OutF[oi] = res;
    }
}

// ---------------------------------------------------------------- launch
extern "C" void kernel_launch(void* const* d_in, const int* in_sizes, int n_in,
                              void* d_out, int out_size, void* d_ws, size_t ws_size,
                              hipStream_t stream) {
    const float* x  = (const float*)d_in[0];
    const void*  ei = d_in[1];
    const float* W1 = (const float*)d_in[2];
    const float* b1 = (const float*)d_in[3];
    const float* W2 = (const float*)d_in[4];
    const float* b2 = (const float*)d_in[5];
    float* out = (float*)d_out;
    const int E = in_sizes[1] / 2;

    char* p = (char*)d_ws;
    auto alloc = [&](size_t bytes) { char* q = p; p += (bytes + 255) & ~(size_t)255; return q; };
    int*    deg    = (int*)alloc((size_t)NNODE * 4);
    int*    rowcnt = (int*)alloc((size_t)NNODE * 4);
    int*    flag   = (int*)alloc(256);
    int*    colsA  = (int*)alloc((size_t)NNODE * KCAP * 4);
    float*  wA     = (float*)alloc((size_t)NNODE * KCAP * 4);
    float*  rsum   = (float*)alloc((size_t)NNODE * 4);
    __bf16* xhi    = (__bf16*)alloc((size_t)NNODE * 512 * 2);
    __bf16* xlo    = (__bf16*)alloc((size_t)NNODE * 512 * 2);
    __bf16* w1Thi  = (__bf16*)alloc((size_t)512 * NHID * 2);
    __bf16* w1Tlo  = (__bf16*)alloc((size_t)512 * NHID * 2);
    __bf16* w2Thi  = (__bf16*)alloc((size_t)NHID * NHID * 2);
    __bf16* w2Tlo  = (__bf16*)alloc((size_t)NHID * NHID * 2);
    __bf16* X1hi   = (__bf16*)alloc((size_t)NNODE * NHID * 2);
    __bf16* X1lo   = (__bf16*)alloc((size_t)NNODE * NHID * 2);
    __bf16* Hhi    = (__bf16*)alloc((size_t)NNODE * NHID * 2);
    __bf16* Hlo    = (__bf16*)alloc((size_t)NNODE * NHID * 2);
    int* nbr = (int*)X1hi;   // aliases X1hi/X1lo; dead before GEMM1 writes X1

    k_init<<<(NNODE + 255) / 256, 256, 0, stream>>>(deg, rowcnt, flag, ei);
    k_build<<<(E + NNODE + 255) / 256, 256, 0, stream>>>(ei, flag, rowcnt, nbr, deg, E);
    k_dedup<<<NNODE, 128, 0, stream>>>(nbr, rowcnt, deg, colsA, wA, rsum);

    k_split4<<<(NNODE * 512 / 4 + 255) / 256, 256, 0, stream>>>(x, xhi, xlo, NNODE * 512 / 4);
    k_splitT<<<(512 * NHID + 255) / 256, 256, 0, stream>>>(W1, w1Thi, w1Tlo, 512);
    k_splitT<<<(NHID * NHID + 255) / 256, 256, 0, stream>>>(W2, w2Thi, w2Tlo, 256);

    k_gemm_mfma<<<dim3(NNODE / 64, NHID / 64), 256, 0, stream>>>(xhi, xlo, w1Thi, w1Tlo, X1hi, X1lo, 512);
    k_medoid<<<NNODE, 256, 0, stream>>>(X1hi, X1lo, b1, nullptr, Hhi, Hlo, colsA, wA, rsum, 1);
    k_gemm_mfma<<<dim3(NNODE / 64, NHID / 64), 256, 0, stream>>>(Hhi, Hlo, w2Thi, w2Tlo, X1hi, X1lo, 256);
    k_medoid<<<NNODE, 256, 0, stream>>>(X1hi, X1lo, b2, out, nullptr, nullptr, colsA, wA, rsum, 0);
}

// Round 4
// 229.364 us; speedup vs baseline: 1.6777x; 1.2999x over previous
//
#include <hip/hip_runtime.h>

typedef _Float16 half2v __attribute__((ext_vector_type(2)));
typedef _Float16 half4 __attribute__((ext_vector_type(4)));
typedef _Float16 half8 __attribute__((ext_vector_type(8)));
typedef float f32x4 __attribute__((ext_vector_type(4)));

#define NNODE 8192
#define NHID  256
#define RCAP  128
#define KCAP  64

// ---------------------------------------------------------------- init + dtype probe
__global__ void k_init(int* deg, int* rowcnt, int* flag, const void* edges) {
    int i = blockIdx.x * blockDim.x + threadIdx.x;
    if (i < NNODE) { deg[i] = 0; rowcnt[i] = 0; }
    if (i == 0) {
        const long long* e = (const long long*)edges;
        int ok = 1;
        for (int k = 0; k < 64; ++k) { long long v = e[k]; if (v < 0 || v >= NNODE) ok = 0; }
        *flag = ok;
    }
}

// ---------------------------------------------------------------- scatter edges
__global__ void k_build(const void* edges, const int* flag, int* rowcnt, int* nbr,
                        int* deg, int E) {
    int i = blockIdx.x * blockDim.x + threadIdx.x;
    int total = E + NNODE;
    if (i >= total) return;
    int r, c;
    if (i < E) {
        if (*flag) {
            const long long* e = (const long long*)edges;
            r = (int)e[i]; c = (int)e[E + i];
        } else {
            const int* e = (const int*)edges;
            r = e[i]; c = e[E + i];
        }
    } else { r = i - E; c = r; }
    int pos = atomicAdd(&rowcnt[r], 1);
    if (pos < RCAP) nbr[r * RCAP + pos] = c;
    atomicAdd(&deg[c], 1);
}

// ---------------------------------------------------------------- dedup + weights + top-64 (wave-parallel)
__global__ __launch_bounds__(128) void k_dedup(const int* __restrict__ nbr,
                                               const int* __restrict__ rowcnt,
                                               const int* __restrict__ deg,
                                               int* __restrict__ cols,
                                               float* __restrict__ wout,
                                               float* __restrict__ rsum) {
    __shared__ int lc[RCAP];
    __shared__ float lw[RCAP];
    __shared__ unsigned char kp[RCAP];
    __shared__ int s_cw[2];
    __shared__ float s_rw[2];
    const int r = blockIdx.x, t = threadIdx.x;
    const int wid = t >> 6, lane = t & 63;
    int n = rowcnt[r]; if (n > RCAP) n = RCAP;
    if (t < n) lc[t] = nbr[r * RCAP + t];
    __syncthreads();
    float dr = 1.f / sqrtf((float)deg[r]);
    bool keep = false; float wv = 0.f;
    if (t < n) {
        int c = lc[t];
        int mult = 0; bool first = true;
        for (int i = 0; i < n; ++i) {
            int ci = lc[i];
            if (ci == c) { mult++; if (i < t) first = false; }
        }
        keep = first;
        if (first) wv = (float)mult * dr * (1.f / sqrtf((float)deg[c]));
    }
    kp[t] = keep ? 1 : 0; lw[t] = wv;
    float rv = wv;
#pragma unroll
    for (int d = 1; d < 64; d <<= 1) rv += __shfl_xor(rv, d, 64);
    unsigned long long b = __ballot(keep);
    int pre = __popcll(b & ((1ull << lane) - 1ull));
    int cw = __popcll(b);
    if (lane == 0) { s_cw[wid] = cw; s_rw[wid] = rv; }
    __syncthreads();
    int total = s_cw[0] + s_cw[1];
    if (t == 0) rsum[r] = s_rw[0] + s_rw[1];
    const int base = r * KCAP;
    if (total <= KCAP) {
        int off = (wid ? s_cw[0] : 0) + pre;
        if (keep) { cols[base + off] = lc[t]; wout[base + off] = wv; }
        for (int m = total + t; m < KCAP; m += 128) { cols[base + m] = r; wout[base + m] = 0.f; }
    } else if (t == 0) {
        for (int s = 0; s < KCAP; ++s) {
            int best = -1;
            for (int i = 0; i < n; ++i) {
                if (!kp[i]) continue;
                if (best < 0 || lw[i] > lw[best] ||
                    (lw[i] == lw[best] && lc[i] < lc[best])) best = i;
            }
            cols[base + s] = lc[best]; wout[base + s] = lw[best]; kp[best] = 0;
        }
    }
}

// ---------------------------------------------------------------- W split+transpose (fp16 hi/lo)
__global__ void k_splitT(const float* __restrict__ W, _Float16* __restrict__ hiT,
                         _Float16* __restrict__ loT, int Kdim) {
    int idx = blockIdx.x * 256 + threadIdx.x;
    if (idx >= Kdim * NHID) return;
    int k = idx >> 8, n = idx & 255;
    float v = W[idx];
    _Float16 h = (_Float16)v;
    hiT[(size_t)n * Kdim + k] = h;
    loT[(size_t)n * Kdim + k] = (_Float16)(v - (float)h);
}

// ---------------------------------------------------------------- fp16 MFMA GEMM  C[M x 256] = A[M x K] * B[K x 256]
// A: fp32 (split in staging, af32=1) or fp16 hi/lo (af32=0). B: pre-split-transposed fp16 [256][K].
// 3-product hi/lo fp16 -> error ~2^-22.  Output: fp16 hi only.
#define GLS 72   // fp16 row stride: 144B = 9 quads -> conflict-free frag reads

__global__ __launch_bounds__(256) void k_gemm(
    const float* __restrict__ Af32,
    const _Float16* __restrict__ Ahi, const _Float16* __restrict__ Alo,
    const _Float16* __restrict__ BThi, const _Float16* __restrict__ BTlo,
    _Float16* __restrict__ Chi, int K, int af32) {
    __shared__ _Float16 sA[2][64][GLS];
    __shared__ _Float16 sB[2][64][GLS];
    const int t = threadIdx.x;
    const int bm = blockIdx.x * 64, bn = blockIdx.y * 64;
    const int lane = t & 63, L15 = lane & 15, q = lane >> 4;
    const int w = t >> 6, wr = w >> 1, wc = w & 1;
    f32x4 acc[2][2];
#pragma unroll
    for (int a = 0; a < 2; ++a)
#pragma unroll
        for (int b = 0; b < 2; ++b) acc[a][b] = (f32x4){0.f, 0.f, 0.f, 0.f};

    for (int k0 = 0; k0 < K; k0 += 64) {
        if (af32) {
#pragma unroll
            for (int i = 0; i < 4; ++i) {
                int row = i * 16 + (t >> 4), kc = (t & 15) * 4;
                float4 v = *(const float4*)(Af32 + (size_t)(bm + row) * K + k0 + kc);
                half4 h, l;
                h[0] = (_Float16)v.x; h[1] = (_Float16)v.y; h[2] = (_Float16)v.z; h[3] = (_Float16)v.w;
                l[0] = (_Float16)(v.x - (float)h[0]); l[1] = (_Float16)(v.y - (float)h[1]);
                l[2] = (_Float16)(v.z - (float)h[2]); l[3] = (_Float16)(v.w - (float)h[3]);
                *(half4*)&sA[0][row][kc] = h;
                *(half4*)&sA[1][row][kc] = l;
            }
        } else {
#pragma unroll
            for (int i = 0; i < 2; ++i) {
                int row = i * 32 + (t >> 3), ch = t & 7;
                size_t ga = (size_t)(bm + row) * K + k0 + ch * 8;
                *(half8*)&sA[0][row][ch * 8] = *(const half8*)(Ahi + ga);
                *(half8*)&sA[1][row][ch * 8] = *(const half8*)(Alo + ga);
            }
        }
#pragma unroll
        for (int i = 0; i < 2; ++i) {
            int row = i * 32 + (t >> 3), ch = t & 7;
            size_t gb = (size_t)(bn + row) * K + k0 + ch * 8;
            *(half8*)&sB[0][row][ch * 8] = *(const half8*)(BThi + gb);
            *(half8*)&sB[1][row][ch * 8] = *(const half8*)(BTlo + gb);
        }
        __syncthreads();
#pragma unroll
        for (int ks = 0; ks < 2; ++ks) {
            const int ko = ks * 32 + q * 8;
            half8 ah[2], al[2], bh[2], bl[2];
#pragma unroll
            for (int tr = 0; tr < 2; ++tr) {
                ah[tr] = *(const half8*)&sA[0][32 * wr + 16 * tr + L15][ko];
                al[tr] = *(const half8*)&sA[1][32 * wr + 16 * tr + L15][ko];
            }
#pragma unroll
            for (int tc = 0; tc < 2; ++tc) {
                bh[tc] = *(const half8*)&sB[0][32 * wc + 16 * tc + L15][ko];
                bl[tc] = *(const half8*)&sB[1][32 * wc + 16 * tc + L15][ko];
            }
#pragma unroll
            for (int tr = 0; tr < 2; ++tr)
#pragma unroll
                for (int tc = 0; tc < 2; ++tc) {
                    acc[tr][tc] = __builtin_amdgcn_mfma_f32_16x16x32_f16(ah[tr], bh[tc], acc[tr][tc], 0, 0, 0);
                    acc[tr][tc] = __builtin_amdgcn_mfma_f32_16x16x32_f16(ah[tr], bl[tc], acc[tr][tc], 0, 0, 0);
                    acc[tr][tc] = __builtin_amdgcn_mfma_f32_16x16x32_f16(al[tr], bh[tc], acc[tr][tc], 0, 0, 0);
                }
        }
        __syncthreads();
    }
#pragma unroll
    for (int tr = 0; tr < 2; ++tr)
#pragma unroll
        for (int tc = 0; tc < 2; ++tc)
#pragma unroll
            for (int r = 0; r < 4; ++r) {
                int rowg = bm + 32 * wr + 16 * tr + q * 4 + r;
                int colg = bn + 32 * wc + 16 * tc + L15;
                Chi[(size_t)rowg * NHID + colg] = (_Float16)acc[tr][tc][r];
            }
}

// ---------------------------------------------------------------- fused soft-k-medoid + bias + relu
// fp16 single-product Gram (2^-12 input rounding -> dist err ~3e-4): no lo array needed.
#define MS 264   // fp16 row stride: 528B = 33 quads -> conflict-free

__global__ __launch_bounds__(256, 4) void k_medoid(
    const _Float16* __restrict__ Xhi,
    const float* __restrict__ bias,
    float* __restrict__ OutF, _Float16* __restrict__ OutHi, _Float16* __restrict__ OutLo,
    const int* __restrict__ cols, const float* __restrict__ wts,
    const float* __restrict__ rsum, int writeHL) {
    __shared__ _Float16 sh[64][MS];
    __shared__ float s_a[64];
    __shared__ float s_sq[64];
    __shared__ float s_cpart[2][64];
    __shared__ float s_u[64];
    __shared__ int   s_cols[64];
    __shared__ float2 s_part[128];

    const int node = blockIdx.x;
    const int t = threadIdx.x;
    const int w = t >> 6, lane = t & 63;
    const int L15 = lane & 15, q = lane >> 4;
    const int wr = w >> 1, wc = w & 1;

    if (t < 64) { s_cols[t] = cols[node * KCAP + t]; s_a[t] = wts[node * KCAP + t]; }
    __syncthreads();

    // gather: 64 rows x 256 dims fp16, 16B chunks (32 per row), coalesced per row
    {
        const int ch = t & 31, rr = t >> 5;
#pragma unroll
        for (int i = 0; i < 8; ++i) {
            int l = i * 8 + rr;
            *(half8*)&sh[l][ch * 8] = *(const half8*)(Xhi + ((size_t)s_cols[l] << 8) + ch * 8);
        }
    }
    __syncthreads();

    // Gram: wave = one 32x32 quadrant (2x2 of 16x16), single fp16 product, K=256
    f32x4 acc[2][2];
#pragma unroll
    for (int a = 0; a < 2; ++a)
#pragma unroll
        for (int b = 0; b < 2; ++b) acc[a][b] = (f32x4){0.f, 0.f, 0.f, 0.f};
#pragma unroll
    for (int ks = 0; ks < 8; ++ks) {
        const int ko = ks * 32 + q * 8;
        half8 ah[2], bh[2];
#pragma unroll
        for (int tr = 0; tr < 2; ++tr) ah[tr] = *(const half8*)&sh[32 * wr + 16 * tr + L15][ko];
#pragma unroll
        for (int tc = 0; tc < 2; ++tc) bh[tc] = *(const half8*)&sh[32 * wc + 16 * tc + L15][ko];
#pragma unroll
        for (int tr = 0; tr < 2; ++tr)
#pragma unroll
            for (int tc = 0; tc < 2; ++tc)
                acc[tr][tc] = __builtin_amdgcn_mfma_f32_16x16x32_f16(ah[tr], bh[tc], acc[tr][tc], 0, 0, 0);
    }

    // diagonal -> s_sq (waves 0 and 3 own diagonal tiles)
#pragma unroll
    for (int tr = 0; tr < 2; ++tr)
#pragma unroll
        for (int tc = 0; tc < 2; ++tc)
            if (32 * wr + 16 * tr == 32 * wc + 16 * tc) {
#pragma unroll
                for (int r = 0; r < 4; ++r)
                    if (L15 == q * 4 + r) s_sq[32 * wr + 16 * tr + L15] = acc[tr][tc][r];
            }
    __syncthreads();

    // dist + weighted column sums c[j] = sum_l a[l] * dist(l,j)
#pragma unroll
    for (int tc = 0; tc < 2; ++tc) {
        const int colg = 32 * wc + 16 * tc + L15;
        const float sqc = s_sq[colg];
        float pj = 0.f;
#pragma unroll
        for (int tr = 0; tr < 2; ++tr)
#pragma unroll
            for (int r = 0; r < 4; ++r) {
                int rowg = 32 * wr + 16 * tr + q * 4 + r;
                float d2 = s_sq[rowg] + sqc - 2.f * acc[tr][tc][r];
                float dist = d2 > 0.f ? sqrtf(d2) : 0.f;
                pj = fmaf(s_a[rowg], dist, pj);
            }
        pj += __shfl_xor(pj, 16, 64);
        pj += __shfl_xor(pj, 32, 64);
        if (q == 0) s_cpart[wr][colg] = pj;
    }
    __syncthreads();

    // softmax(-c) * a, renormalized (softmax denom cancels), * row_sum
    if (w == 0) {
        int j = lane;
        float c = s_cpart[0][j] + s_cpart[1][j];
        float aj = s_a[j];
        bool valid = aj > 0.f;
        float cv = valid ? c : 3.4e38f;
        float mn = cv;
#pragma unroll
        for (int d = 1; d < 64; d <<= 1) mn = fminf(mn, __shfl_xor(mn, d, 64));
        float e = valid ? __expf(mn - c) * aj : 0.f;
        float s = e;
#pragma unroll
        for (int d = 1; d < 64; d <<= 1) s += __shfl_xor(s, d, 64);
        s_u[j] = e * (rsum[node] / s);
    }
    __syncthreads();

    // epilogue: out[d] = sum_j u[j]*x_j[d].  dim-pair b32 reads (read2-mergeable),
    // waves 0,1: j 0..31 / dims (w&1)*128..; waves 2,3: j 32..63, partial combine.
    const int jbase = (w >> 1) * 32;
    const int dp = lane + 64 * (w & 1);      // dim-pair index 0..127
    float ox = 0.f, oy = 0.f;
#pragma unroll
    for (int j = 0; j < 32; ++j) {
        float u = s_u[jbase + j];
        half2v v = *(const half2v*)&sh[jbase + j][2 * dp];
        ox = fmaf(u, (float)v[0], ox);
        oy = fmaf(u, (float)v[1], oy);
    }
    if (w >= 2) s_part[dp] = make_float2(ox, oy);
    __syncthreads();
    if (w < 2) {
        float2 pp = s_part[dp];
        ox += pp.x; oy += pp.y;
        const int d0 = 2 * dp;
        float rx = fmaxf(ox + bias[d0], 0.f);
        float ry = fmaxf(oy + bias[d0 + 1], 0.f);
        size_t oi = (size_t)node * NHID + d0;
        if (writeHL) {
            _Float16 hx = (_Float16)rx, hy = (_Float16)ry;
            half2v hv = {hx, hy};
            half2v lv = {(_Float16)(rx - (float)hx), (_Float16)(ry - (float)hy)};
            *(half2v*)&OutHi[oi] = hv;
            *(half2v*)&OutLo[oi] = lv;
        } else {
            float2 o2 = make_float2(rx, ry);
            *(float2*)&OutF[oi] = o2;
        }
    }
}

// ---------------------------------------------------------------- launch
extern "C" void kernel_launch(void* const* d_in, const int* in_sizes, int n_in,
                              void* d_out, int out_size, void* d_ws, size_t ws_size,
                              hipStream_t stream) {
    const float* x  = (const float*)d_in[0];
    const void*  ei = d_in[1];
    const float* W1 = (const float*)d_in[2];
    const float* b1 = (const float*)d_in[3];
    const float* W2 = (const float*)d_in[4];
    const float* b2 = (const float*)d_in[5];
    float* out = (float*)d_out;
    const int E = in_sizes[1] / 2;

    char* p = (char*)d_ws;
    auto alloc = [&](size_t bytes) { char* q = p; p += (bytes + 255) & ~(size_t)255; return q; };
    int*      deg    = (int*)alloc((size_t)NNODE * 4);
    int*      rowcnt = (int*)alloc((size_t)NNODE * 4);
    int*      flag   = (int*)alloc(256);
    int*      colsA  = (int*)alloc((size_t)NNODE * KCAP * 4);
    float*    wA     = (float*)alloc((size_t)NNODE * KCAP * 4);
    float*    rsum   = (float*)alloc((size_t)NNODE * 4);
    _Float16* w1Thi  = (_Float16*)alloc((size_t)512 * NHID * 2);
    _Float16* w1Tlo  = (_Float16*)alloc((size_t)512 * NHID * 2);
    _Float16* w2Thi  = (_Float16*)alloc((size_t)NHID * NHID * 2);
    _Float16* w2Tlo  = (_Float16*)alloc((size_t)NHID * NHID * 2);
    _Float16* X1hi   = (_Float16*)alloc((size_t)NNODE * NHID * 2);   // also X2hi
    _Float16* Hhi    = (_Float16*)alloc((size_t)NNODE * NHID * 2);
    _Float16* Hlo    = (_Float16*)alloc((size_t)NNODE * NHID * 2);
    int* nbr = (int*)alloc((size_t)NNODE * RCAP * 4);   // dead after k_dedup

    k_init<<<(NNODE + 255) / 256, 256, 0, stream>>>(deg, rowcnt, flag, ei);
    k_build<<<(E + NNODE + 255) / 256, 256, 0, stream>>>(ei, flag, rowcnt, nbr, deg, E);
    k_dedup<<<NNODE, 128, 0, stream>>>(nbr, rowcnt, deg, colsA, wA, rsum);

    k_splitT<<<(512 * NHID + 255) / 256, 256, 0, stream>>>(W1, w1Thi, w1Tlo, 512);
    k_splitT<<<(NHID * NHID + 255) / 256, 256, 0, stream>>>(W2, w2Thi, w2Tlo, 256);

    k_gemm<<<dim3(NNODE / 64, NHID / 64), 256, 0, stream>>>(
        x, nullptr, nullptr, w1Thi, w1Tlo, X1hi, 512, 1);
    k_medoid<<<NNODE, 256, 0, stream>>>(X1hi, b1, nullptr, Hhi, Hlo, colsA, wA, rsum, 1);
    k_gemm<<<dim3(NNODE / 64, NHID / 64), 256, 0, stream>>>(
        nullptr, Hhi, Hlo, w2Thi, w2Tlo, X1hi, 256, 0);
    k_medoid<<<NNODE, 256, 0, stream>>>(X1hi, b2, out, nullptr, nullptr, colsA, wA, rsum, 0);
}

// Round 5
// 218.383 us; speedup vs baseline: 1.7621x; 1.0503x over previous
//
#include <hip/hip_runtime.h>

typedef _Float16 half2v __attribute__((ext_vector_type(2)));
typedef _Float16 half4 __attribute__((ext_vector_type(4)));
typedef _Float16 half8 __attribute__((ext_vector_type(8)));
typedef float f32x4 __attribute__((ext_vector_type(4)));

#define NNODE 8192
#define NHID  256
#define RCAP  128
#define KCAP  64

// ---------------------------------------------------------------- init + dtype probe
__global__ void k_init(int* deg, int* rowcnt, int* flag, const void* edges) {
    int i = blockIdx.x * blockDim.x + threadIdx.x;
    if (i < NNODE) { deg[i] = 0; rowcnt[i] = 0; }
    if (i == 0) {
        const long long* e = (const long long*)edges;
        int ok = 1;
        for (int k = 0; k < 64; ++k) { long long v = e[k]; if (v < 0 || v >= NNODE) ok = 0; }
        *flag = ok;
    }
}

// ---------------------------------------------------------------- scatter edges
__global__ void k_build(const void* edges, const int* flag, int* rowcnt, int* nbr,
                        int* deg, int E) {
    int i = blockIdx.x * blockDim.x + threadIdx.x;
    int total = E + NNODE;
    if (i >= total) return;
    int r, c;
    if (i < E) {
        if (*flag) {
            const long long* e = (const long long*)edges;
            r = (int)e[i]; c = (int)e[E + i];
        } else {
            const int* e = (const int*)edges;
            r = e[i]; c = e[E + i];
        }
    } else { r = i - E; c = r; }
    int pos = atomicAdd(&rowcnt[r], 1);
    if (pos < RCAP) nbr[r * RCAP + pos] = c;
    atomicAdd(&deg[c], 1);
}

// ---------------------------------------------------------------- dedup + weights + top-64 (wave-parallel)
__global__ __launch_bounds__(128) void k_dedup(const int* __restrict__ nbr,
                                               const int* __restrict__ rowcnt,
                                               const int* __restrict__ deg,
                                               int* __restrict__ cols,
                                               float* __restrict__ wout,
                                               float* __restrict__ rsum) {
    __shared__ int lc[RCAP];
    __shared__ float lw[RCAP];
    __shared__ unsigned char kp[RCAP];
    __shared__ int s_cw[2];
    __shared__ float s_rw[2];
    const int r = blockIdx.x, t = threadIdx.x;
    const int wid = t >> 6, lane = t & 63;
    int n = rowcnt[r]; if (n > RCAP) n = RCAP;
    if (t < n) lc[t] = nbr[r * RCAP + t];
    __syncthreads();
    float dr = 1.f / sqrtf((float)deg[r]);
    bool keep = false; float wv = 0.f;
    if (t < n) {
        int c = lc[t];
        int mult = 0; bool first = true;
        for (int i = 0; i < n; ++i) {
            int ci = lc[i];
            if (ci == c) { mult++; if (i < t) first = false; }
        }
        keep = first;
        if (first) wv = (float)mult * dr * (1.f / sqrtf((float)deg[c]));
    }
    kp[t] = keep ? 1 : 0; lw[t] = wv;
    float rv = wv;
#pragma unroll
    for (int d = 1; d < 64; d <<= 1) rv += __shfl_xor(rv, d, 64);
    unsigned long long b = __ballot(keep);
    int pre = __popcll(b & ((1ull << lane) - 1ull));
    int cw = __popcll(b);
    if (lane == 0) { s_cw[wid] = cw; s_rw[wid] = rv; }
    __syncthreads();
    int total = s_cw[0] + s_cw[1];
    if (t == 0) rsum[r] = s_rw[0] + s_rw[1];
    const int base = r * KCAP;
    if (total <= KCAP) {
        int off = (wid ? s_cw[0] : 0) + pre;
        if (keep) { cols[base + off] = lc[t]; wout[base + off] = wv; }
        for (int m = total + t; m < KCAP; m += 128) { cols[base + m] = r; wout[base + m] = 0.f; }
    } else if (t == 0) {
        for (int s = 0; s < KCAP; ++s) {
            int best = -1;
            for (int i = 0; i < n; ++i) {
                if (!kp[i]) continue;
                if (best < 0 || lw[i] > lw[best] ||
                    (lw[i] == lw[best] && lc[i] < lc[best])) best = i;
            }
            cols[base + s] = lc[best]; wout[base + s] = lw[best]; kp[best] = 0;
        }
    }
}

// ---------------------------------------------------------------- W split+transpose (fp16)
__global__ void k_splitT(const float* __restrict__ W, _Float16* __restrict__ hiT, int Kdim) {
    int idx = blockIdx.x * 256 + threadIdx.x;
    if (idx >= Kdim * NHID) return;
    int k = idx >> 8, n = idx & 255;
    hiT[(size_t)n * Kdim + k] = (_Float16)W[idx];
}

// ---------------------------------------------------------------- fp16 MFMA GEMM  C[M x 256] = A[M x K] * B[K x 256]
// Single-product fp16 (fp32 accumulate): error ~1e-4, below the fp16 rounding
// the medoid consumer applies anyway. B pre-split-transposed fp16 [256][K].
#define GLS 72   // fp16 row stride: 144B = 9 quads -> conflict-free frag reads

__global__ __launch_bounds__(256) void k_gemm(
    const float* __restrict__ Af32, const _Float16* __restrict__ Ahi,
    const _Float16* __restrict__ BT, _Float16* __restrict__ Chi, int K, int af32) {
    __shared__ _Float16 sA[64][GLS];
    __shared__ _Float16 sB[64][GLS];
    const int t = threadIdx.x;
    const int bm = blockIdx.x * 64, bn = blockIdx.y * 64;
    const int lane = t & 63, L15 = lane & 15, q = lane >> 4;
    const int w = t >> 6, wr = w >> 1, wc = w & 1;
    f32x4 acc[2][2];
#pragma unroll
    for (int a = 0; a < 2; ++a)
#pragma unroll
        for (int b = 0; b < 2; ++b) acc[a][b] = (f32x4){0.f, 0.f, 0.f, 0.f};

    for (int k0 = 0; k0 < K; k0 += 64) {
        if (af32) {
#pragma unroll
            for (int i = 0; i < 4; ++i) {
                int row = i * 16 + (t >> 4), kc = (t & 15) * 4;
                float4 v = *(const float4*)(Af32 + (size_t)(bm + row) * K + k0 + kc);
                half4 h;
                h[0] = (_Float16)v.x; h[1] = (_Float16)v.y;
                h[2] = (_Float16)v.z; h[3] = (_Float16)v.w;
                *(half4*)&sA[row][kc] = h;
            }
        } else {
#pragma unroll
            for (int i = 0; i < 2; ++i) {
                int row = i * 32 + (t >> 3), ch = t & 7;
                *(half8*)&sA[row][ch * 8] =
                    *(const half8*)(Ahi + (size_t)(bm + row) * K + k0 + ch * 8);
            }
        }
#pragma unroll
        for (int i = 0; i < 2; ++i) {
            int row = i * 32 + (t >> 3), ch = t & 7;
            *(half8*)&sB[row][ch * 8] =
                *(const half8*)(BT + (size_t)(bn + row) * K + k0 + ch * 8);
        }
        __syncthreads();
#pragma unroll
        for (int ks = 0; ks < 2; ++ks) {
            const int ko = ks * 32 + q * 8;
            half8 ah[2], bh[2];
#pragma unroll
            for (int tr = 0; tr < 2; ++tr)
                ah[tr] = *(const half8*)&sA[32 * wr + 16 * tr + L15][ko];
#pragma unroll
            for (int tc = 0; tc < 2; ++tc)
                bh[tc] = *(const half8*)&sB[32 * wc + 16 * tc + L15][ko];
#pragma unroll
            for (int tr = 0; tr < 2; ++tr)
#pragma unroll
                for (int tc = 0; tc < 2; ++tc)
                    acc[tr][tc] = __builtin_amdgcn_mfma_f32_16x16x32_f16(ah[tr], bh[tc], acc[tr][tc], 0, 0, 0);
        }
        __syncthreads();
    }
#pragma unroll
    for (int tr = 0; tr < 2; ++tr)
#pragma unroll
        for (int tc = 0; tc < 2; ++tc)
#pragma unroll
            for (int r = 0; r < 4; ++r) {
                int rowg = bm + 32 * wr + 16 * tr + q * 4 + r;
                int colg = bn + 32 * wc + 16 * tc + L15;
                Chi[(size_t)rowg * NHID + colg] = (_Float16)acc[tr][tc][r];
            }
}

// ---------------------------------------------------------------- fused soft-k-medoid + bias + relu
#define MS 264   // fp16 row stride: 528B = 33 quads -> conflict-free

__global__ __launch_bounds__(256, 4) void k_medoid(
    const _Float16* __restrict__ Xhi,
    const float* __restrict__ bias,
    float* __restrict__ OutF, _Float16* __restrict__ OutHi,
    const int* __restrict__ cols, const float* __restrict__ wts,
    const float* __restrict__ rsum, int writeH) {
    __shared__ _Float16 sh[64][MS];
    __shared__ float s_a[64];
    __shared__ float s_sq[64];
    __shared__ float s_cpart[2][64];
    __shared__ float s_u[64];
    __shared__ int   s_cols[64];
    __shared__ float s_red[4][288];   // [wave][9*oct+e] padded stride

    const int node = blockIdx.x;
    const int t = threadIdx.x;
    const int w = t >> 6, lane = t & 63;
    const int L15 = lane & 15, q = lane >> 4;
    const int wr = w >> 1, wc = w & 1;

    if (t < 64) { s_cols[t] = cols[node * KCAP + t]; s_a[t] = wts[node * KCAP + t]; }
    __syncthreads();

    // gather: 64 rows x 256 dims fp16, 16B chunks, coalesced per row
    {
        const int ch = t & 31, rr = t >> 5;
#pragma unroll
        for (int i = 0; i < 8; ++i) {
            int l = i * 8 + rr;
            *(half8*)&sh[l][ch * 8] = *(const half8*)(Xhi + ((size_t)s_cols[l] << 8) + ch * 8);
        }
    }
    __syncthreads();

    // Gram: wave = one 32x32 quadrant (2x2 of 16x16), single fp16 product, K=256
    f32x4 acc[2][2];
#pragma unroll
    for (int a = 0; a < 2; ++a)
#pragma unroll
        for (int b = 0; b < 2; ++b) acc[a][b] = (f32x4){0.f, 0.f, 0.f, 0.f};
#pragma unroll
    for (int ks = 0; ks < 8; ++ks) {
        const int ko = ks * 32 + q * 8;
        half8 ah[2], bh[2];
#pragma unroll
        for (int tr = 0; tr < 2; ++tr) ah[tr] = *(const half8*)&sh[32 * wr + 16 * tr + L15][ko];
#pragma unroll
        for (int tc = 0; tc < 2; ++tc) bh[tc] = *(const half8*)&sh[32 * wc + 16 * tc + L15][ko];
#pragma unroll
        for (int tr = 0; tr < 2; ++tr)
#pragma unroll
            for (int tc = 0; tc < 2; ++tc)
                acc[tr][tc] = __builtin_amdgcn_mfma_f32_16x16x32_f16(ah[tr], bh[tc], acc[tr][tc], 0, 0, 0);
    }

    // diagonal -> s_sq
#pragma unroll
    for (int tr = 0; tr < 2; ++tr)
#pragma unroll
        for (int tc = 0; tc < 2; ++tc)
            if (32 * wr + 16 * tr == 32 * wc + 16 * tc) {
#pragma unroll
                for (int r = 0; r < 4; ++r)
                    if (L15 == q * 4 + r) s_sq[32 * wr + 16 * tr + L15] = acc[tr][tc][r];
            }
    __syncthreads();

    // dist + weighted column sums c[j] = sum_l a[l] * dist(l,j)   (raw v_sqrt, no fixup)
#pragma unroll
    for (int tc = 0; tc < 2; ++tc) {
        const int colg = 32 * wc + 16 * tc + L15;
        const float sqc = s_sq[colg];
        float pj = 0.f;
#pragma unroll
        for (int tr = 0; tr < 2; ++tr)
#pragma unroll
            for (int r = 0; r < 4; ++r) {
                int rowg = 32 * wr + 16 * tr + q * 4 + r;
                float d2 = s_sq[rowg] + sqc - 2.f * acc[tr][tc][r];
                float dist = d2 > 0.f ? __builtin_amdgcn_sqrtf(d2) : 0.f;
                pj = fmaf(s_a[rowg], dist, pj);
            }
        pj += __shfl_xor(pj, 16, 64);
        pj += __shfl_xor(pj, 32, 64);
        if (q == 0) s_cpart[wr][colg] = pj;
    }
    __syncthreads();

    // softmax(-c) * a, renormalized (softmax denom cancels), * row_sum
    if (w == 0) {
        int j = lane;
        float c = s_cpart[0][j] + s_cpart[1][j];
        float aj = s_a[j];
        bool valid = aj > 0.f;
        float cv = valid ? c : 3.4e38f;
        float mn = cv;
#pragma unroll
        for (int d = 1; d < 64; d <<= 1) mn = fminf(mn, __shfl_xor(mn, d, 64));
        float e = valid ? __expf(mn - c) * aj : 0.f;
        float s = e;
#pragma unroll
        for (int d = 1; d < 64; d <<= 1) s += __shfl_xor(s, d, 64);
        s_u[j] = e * (rsum[node] / s);
    }
    __syncthreads();

    // epilogue: out[d] = sum_j u[j]*x_j[d].
    // thread = (octet of 8 dims) x (block of 8 j): b128 x-reads, fp32 fma.
    const int oct = t & 31, jb = t >> 5;
    float accd[8] = {0.f, 0.f, 0.f, 0.f, 0.f, 0.f, 0.f, 0.f};
#pragma unroll
    for (int jj = 0; jj < 8; ++jj) {
        int j = jb * 8 + jj;
        float u = s_u[j];
        half8 xv = *(const half8*)&sh[j][8 * oct];
#pragma unroll
        for (int e = 0; e < 8; ++e) accd[e] = fmaf(u, (float)xv[e], accd[e]);
    }
    // fold jb pairs within wave (lanes l, l+32 share oct)
#pragma unroll
    for (int e = 0; e < 8; ++e) accd[e] += __shfl_xor(accd[e], 32, 64);
    if (lane < 32) {
#pragma unroll
        for (int e = 0; e < 8; ++e) s_red[w][9 * oct + e] = accd[e];
    }
    __syncthreads();
    // final: thread t = dim d
    const int idx = 9 * (t >> 3) + (t & 7);
    float o = s_red[0][idx] + s_red[1][idx] + s_red[2][idx] + s_red[3][idx];
    float res = fmaxf(o + bias[t], 0.f);
    size_t oi = (size_t)node * NHID + t;
    if (writeH) OutHi[oi] = (_Float16)res;
    else        OutF[oi] = res;
}

// ---------------------------------------------------------------- launch
extern "C" void kernel_launch(void* const* d_in, const int* in_sizes, int n_in,
                              void* d_out, int out_size, void* d_ws, size_t ws_size,
                              hipStream_t stream) {
    const float* x  = (const float*)d_in[0];
    const void*  ei = d_in[1];
    const float* W1 = (const float*)d_in[2];
    const float* b1 = (const float*)d_in[3];
    const float* W2 = (const float*)d_in[4];
    const float* b2 = (const float*)d_in[5];
    float* out = (float*)d_out;
    const int E = in_sizes[1] / 2;

    char* p = (char*)d_ws;
    auto alloc = [&](size_t bytes) { char* q = p; p += (bytes + 255) & ~(size_t)255; return q; };
    int*      deg    = (int*)alloc((size_t)NNODE * 4);
    int*      rowcnt = (int*)alloc((size_t)NNODE * 4);
    int*      flag   = (int*)alloc(256);
    int*      colsA  = (int*)alloc((size_t)NNODE * KCAP * 4);
    float*    wA     = (float*)alloc((size_t)NNODE * KCAP * 4);
    float*    rsum   = (float*)alloc((size_t)NNODE * 4);
    _Float16* w1T    = (_Float16*)alloc((size_t)512 * NHID * 2);
    _Float16* w2T    = (_Float16*)alloc((size_t)NHID * NHID * 2);
    _Float16* X1hi   = (_Float16*)alloc((size_t)NNODE * NHID * 2);   // also X2
    _Float16* Hhi    = (_Float16*)alloc((size_t)NNODE * NHID * 2);
    int* nbr = (int*)alloc((size_t)NNODE * RCAP * 4);   // dead after k_dedup

    k_init<<<(NNODE + 255) / 256, 256, 0, stream>>>(deg, rowcnt, flag, ei);
    k_build<<<(E + NNODE + 255) / 256, 256, 0, stream>>>(ei, flag, rowcnt, nbr, deg, E);
    k_dedup<<<NNODE, 128, 0, stream>>>(nbr, rowcnt, deg, colsA, wA, rsum);

    k_splitT<<<(512 * NHID + 255) / 256, 256, 0, stream>>>(W1, w1T, 512);
    k_splitT<<<(NHID * NHID + 255) / 256, 256, 0, stream>>>(W2, w2T, 256);

    k_gemm<<<dim3(NNODE / 64, NHID / 64), 256, 0, stream>>>(x, nullptr, w1T, X1hi, 512, 1);
    k_medoid<<<NNODE, 256, 0, stream>>>(X1hi, b1, nullptr, Hhi, colsA, wA, rsum, 1);
    k_gemm<<<dim3(NNODE / 64, NHID / 64), 256, 0, stream>>>(nullptr, Hhi, w2T, X1hi, 256, 0);
    k_medoid<<<NNODE, 256, 0, stream>>>(X1hi, b2, out, nullptr, colsA, wA, rsum, 0);
}